// Round 1
// baseline (3554.548 us; speedup 1.0000x reference)
//
#include <hip/hip_runtime.h>

// FNO forward, fp32 correctness-first implementation.
// Layout conventions:
//  v, s: [C][H][W] float
//  t1/e: [C][H][M] float2 (re, im)   (t1 and e share a buffer)
//  c, c2: [C][M][M] float2
//  tw: cos table [512], sin table [512]

constexpr int Hn = 512, Wn = 512, Cn = 64, Mn = 64, Ln = 4;
constexpr int HWn = Hn * Wn;

__device__ __forceinline__ float gelu_f(float x) {
  // jax.nn.gelu approximate=True: 0.5x(1+tanh(sqrt(2/pi)(x+0.044715x^3)))
  float t = 0.7978845608028654f * (x + 0.044715f * x * x * x);
  float e = __expf(2.0f * t);
  float th = 1.0f - 2.0f / (e + 1.0f);   // tanh(t), safe at +-inf
  return 0.5f * x * (1.0f + th);
}

__global__ __launch_bounds__(512) void k_init_tw(float* __restrict__ tw) {
  int j = threadIdx.x;  // 512 threads
  float ang = 6.283185307179586f * (float)j / 512.0f;
  tw[j] = cosf(ang);
  tw[512 + j] = sinf(ang);
}

__global__ __launch_bounds__(256) void k_encode(const float* __restrict__ u,
                                                const float* __restrict__ x,
                                                const float* __restrict__ ew,
                                                const float* __restrict__ eb,
                                                float* __restrict__ v) {
  __shared__ float w[Cn][3];
  __shared__ float b[Cn];
  int tid = threadIdx.x;
  if (tid < Cn) {
    w[tid][0] = ew[tid * 3 + 0];
    w[tid][1] = ew[tid * 3 + 1];
    w[tid][2] = ew[tid * 3 + 2];
    b[tid] = eb[tid];
  }
  __syncthreads();
  int p = blockIdx.x * 256 + tid;
  float x0 = x[p], x1 = x[HWn + p], uu = u[p];
  #pragma unroll 8
  for (int c = 0; c < Cn; c++)
    v[c * HWn + p] = fmaf(w[c][0], x0, fmaf(w[c][1], x1, fmaf(w[c][2], uu, b[c])));
}

// t1[ch,h,n] = sum_w v[ch,h,w] * exp(-2*pi*i*n*w/512)
// grid: C*H/4 blocks, 256 thr = 4 rows x 64 lanes(n)
__global__ __launch_bounds__(256) void k_fwd1(const float* __restrict__ v,
                                              const float* __restrict__ tw,
                                              float2* __restrict__ t1) {
  __shared__ float twc[512], tws[512];
  __shared__ float rows[4][512];
  int tid = threadIdx.x;
  for (int j = tid; j < 512; j += 256) { twc[j] = tw[j]; tws[j] = tw[512 + j]; }
  int r = tid >> 6, n = tid & 63;
  int row = blockIdx.x * 4 + r;   // row = ch*512 + h
  const float* vr = v + (size_t)row * Wn;
  #pragma unroll
  for (int w8 = 0; w8 < 8; w8++) rows[r][n + 64 * w8] = vr[n + 64 * w8];
  __syncthreads();
  float ac = 0.f, as = 0.f;
  int idx = 0;                     // (n*w) & 511
  #pragma unroll 8
  for (int w = 0; w < 512; w++) {
    float vv = rows[r][w];
    ac = fmaf(vv, twc[idx], ac);
    as = fmaf(vv, tws[idx], as);
    idx = (idx + n) & 511;
  }
  t1[row * 64 + n] = make_float2(ac, -as);
}

// c[ch,m,n] += (1/HW) sum_h t1[ch,h,n] * exp(-2*pi*i*(m-32)*h/512)
// grid: (C, 8 h-chunks), 256 thr = 4 m-groups x 64 lanes(n); atomic accumulate
__global__ __launch_bounds__(256) void k_fwd2(const float2* __restrict__ t1,
                                              const float* __restrict__ tw,
                                              float2* __restrict__ cb) {
  __shared__ float twc[512], tws[512];
  __shared__ float2 tsh[8][64];
  int tid = threadIdx.x;
  for (int j = tid; j < 512; j += 256) { twc[j] = tw[j]; tws[j] = tw[512 + j]; }
  int ch = blockIdx.x, hc = blockIdx.y;
  int n = tid & 63, mg = tid >> 6;
  float accr[16], acci[16];
  #pragma unroll
  for (int k = 0; k < 16; k++) { accr[k] = 0.f; acci[k] = 0.f; }
  for (int h8 = 0; h8 < 8; h8++) {
    __syncthreads();
    for (int j = tid; j < 512; j += 256) {
      int rr = j >> 6, nn = j & 63;
      tsh[rr][nn] = t1[(ch * 512 + hc * 64 + h8 * 8 + rr) * 64 + nn];
    }
    __syncthreads();
    #pragma unroll
    for (int rr = 0; rr < 8; rr++) {
      int h = hc * 64 + h8 * 8 + rr;
      float2 t = tsh[rr][n];
      #pragma unroll
      for (int k = 0; k < 16; k++) {
        int m = mg * 16 + k;
        int idx = ((m - 32) * h) & 511;
        float cc = twc[idx], ss = tws[idx];
        // t * (cos - i sin)
        accr[k] = fmaf(t.x, cc, fmaf(t.y, ss, accr[k]));
        acci[k] = fmaf(t.y, cc, fmaf(-t.x, ss, acci[k]));
      }
    }
  }
  const float sc = 1.0f / 262144.0f;  // 1/(H*W), norm='forward'
  #pragma unroll
  for (int k = 0; k < 16; k++) {
    int m = mg * 16 + k;
    atomicAdd(&cb[(ch * 64 + m) * 64 + n].x, accr[k] * sc);
    atomicAdd(&cb[(ch * 64 + m) * 64 + n].y, acci[k] * sc);
  }
}

// c2[o,m,n] = sum_i A[o,i,m,n] * c[i,m,n]  (complex). Memory-bound on A.
// grid: (M, 16 o-groups), 256 thr = 4 waves (o) x 64 lanes (n)
__global__ __launch_bounds__(256) void k_mix(const float* __restrict__ Ar,
                                             const float* __restrict__ Ai,
                                             const float2* __restrict__ cb,
                                             float2* __restrict__ c2b) {
  __shared__ float2 csh[64][64];   // c[i][n] at fixed m
  int tid = threadIdx.x;
  int m = blockIdx.x, og = blockIdx.y;
  for (int j = tid; j < 4096; j += 256) {
    int i = j >> 6, n = j & 63;
    csh[i][n] = cb[(i * 64 + m) * 64 + n];
  }
  __syncthreads();
  int o = og * 4 + (tid >> 6);
  int n = tid & 63;
  const float* ar = Ar + (size_t)o * 64 * 4096 + m * 64 + n;
  const float* ai = Ai + (size_t)o * 64 * 4096 + m * 64 + n;
  float accr = 0.f, acci = 0.f;
  #pragma unroll 8
  for (int i = 0; i < 64; i++) {
    float a_r = ar[i * 4096];
    float a_i = ai[i * 4096];
    float2 cv = csh[i][n];
    accr = fmaf(a_r, cv.x, fmaf(-a_i, cv.y, accr));
    acci = fmaf(a_r, cv.y, fmaf(a_i, cv.x, acci));
  }
  c2b[(o * 64 + m) * 64 + n] = make_float2(accr, acci);
}

// e[ch,h,n] = sum_m c2[ch,m,n] * exp(+2*pi*i*(m-32)*h/512)
// grid: (C, 8 h-chunks), 256 thr = 4 h-subgroups x 64 lanes(n)
__global__ __launch_bounds__(256) void k_inv1(const float2* __restrict__ c2buf,
                                              const float* __restrict__ tw,
                                              float2* __restrict__ e) {
  __shared__ float twc[512], tws[512];
  __shared__ float2 csh[64][64];
  int tid = threadIdx.x;
  for (int j = tid; j < 512; j += 256) { twc[j] = tw[j]; tws[j] = tw[512 + j]; }
  int ch = blockIdx.x, hc = blockIdx.y;
  for (int j = tid; j < 4096; j += 256) csh[j >> 6][j & 63] = c2buf[ch * 4096 + j];
  __syncthreads();
  int n = tid & 63, hs = tid >> 6;
  for (int k = 0; k < 16; k++) {
    int h = hc * 64 + hs * 16 + k;
    float er = 0.f, ei = 0.f;
    #pragma unroll 8
    for (int mm = 0; mm < 64; mm++) {
      int idx = ((mm - 32) * h) & 511;
      float cc = twc[idx], ss = tws[idx];
      float2 t = csh[mm][n];
      er = fmaf(t.x, cc, fmaf(-t.y, ss, er));
      ei = fmaf(t.y, cc, fmaf(t.x, ss, ei));
    }
    e[(ch * 512 + h) * 64 + n] = make_float2(er, ei);
  }
}

// s[ch,h,w] = Re(e[ch,h,0]) + sum_{n>=1} 2*(Re(e)cos(2pi n w/512) - Im(e)sin(...))
// grid: C*H/4 blocks, 256 thr = 4 rows x 64 lanes(w0); each lane does 8 w's
__global__ __launch_bounds__(256) void k_inv2(const float2* __restrict__ e,
                                              const float* __restrict__ tw,
                                              float* __restrict__ s) {
  __shared__ float twc[512], tws[512];
  __shared__ float er[4][64], ei[4][64];
  int tid = threadIdx.x;
  for (int j = tid; j < 512; j += 256) { twc[j] = tw[j]; tws[j] = tw[512 + j]; }
  int r = tid >> 6, lane = tid & 63;
  int row = blockIdx.x * 4 + r;   // ch*512 + h
  float2 t = e[row * 64 + lane];
  float alpha = (lane == 0) ? 1.0f : 2.0f;  // Hermitian doubling; Im(bin0) dropped
  er[r][lane] = t.x * alpha;
  ei[r][lane] = t.y * alpha;
  __syncthreads();
  float acc[8];
  #pragma unroll
  for (int j = 0; j < 8; j++) acc[j] = 0.f;
  for (int n = 0; n < 64; n++) {
    float R = er[r][n], I = ei[r][n];
    int idx = (n * lane) & 511;
    int step = (n * 64) & 511;
    #pragma unroll
    for (int j = 0; j < 8; j++) {
      acc[j] = fmaf(R, twc[idx], fmaf(-I, tws[idx], acc[j]));
      idx = (idx + step) & 511;
    }
  }
  #pragma unroll
  for (int j = 0; j < 8; j++) s[(size_t)row * 512 + lane + 64 * j] = acc[j];
}

// v[:,p] += gelu(W2 @ gelu(W1 @ s[:,p] + b1) + b2), fused per pixel
__global__ __launch_bounds__(256) void k_conv(const float* __restrict__ s,
                                              float* __restrict__ v,
                                              const float* __restrict__ w1,
                                              const float* __restrict__ b1,
                                              const float* __restrict__ w2,
                                              const float* __restrict__ b2) {
  __shared__ float4 W1[64][16];    // W1[o][i/4]
  __shared__ float W2T[64][64];    // W2T[i][o] = w2[o,i]
  __shared__ float B1[64], B2[64];
  int tid = threadIdx.x;
  float* W1f = (float*)W1;
  for (int j = tid; j < 4096; j += 256) {
    W1f[j] = w1[j];
    W2T[j & 63][j >> 6] = w2[j];
  }
  if (tid < 64) { B1[tid] = b1[tid]; B2[tid] = b2[tid]; }
  __syncthreads();
  int p = blockIdx.x * 256 + tid;
  float sv[64];
  #pragma unroll
  for (int i = 0; i < 64; i++) sv[i] = s[i * HWn + p];
  float acc2[64];
  #pragma unroll
  for (int o = 0; o < 64; o++) acc2[o] = B2[o];
  for (int i = 0; i < 64; i++) {
    float a = B1[i];
    #pragma unroll
    for (int k4 = 0; k4 < 16; k4++) {
      float4 ww = W1[i][k4];
      a = fmaf(ww.x, sv[4 * k4 + 0], a);
      a = fmaf(ww.y, sv[4 * k4 + 1], a);
      a = fmaf(ww.z, sv[4 * k4 + 2], a);
      a = fmaf(ww.w, sv[4 * k4 + 3], a);
    }
    float g = gelu_f(a);
    const float4* w2r = (const float4*)W2T[i];
    #pragma unroll
    for (int o4 = 0; o4 < 16; o4++) {
      float4 ww = w2r[o4];
      acc2[4 * o4 + 0] = fmaf(ww.x, g, acc2[4 * o4 + 0]);
      acc2[4 * o4 + 1] = fmaf(ww.y, g, acc2[4 * o4 + 1]);
      acc2[4 * o4 + 2] = fmaf(ww.z, g, acc2[4 * o4 + 2]);
      acc2[4 * o4 + 3] = fmaf(ww.w, g, acc2[4 * o4 + 3]);
    }
  }
  #pragma unroll
  for (int o = 0; o < 64; o++) v[o * HWn + p] += gelu_f(acc2[o]);
}

__global__ __launch_bounds__(256) void k_decode(const float* __restrict__ v,
                                                const float* __restrict__ dw,
                                                const float* __restrict__ db,
                                                float* __restrict__ out) {
  __shared__ float wsm[64];
  int tid = threadIdx.x;
  if (tid < 64) wsm[tid] = dw[tid];
  __syncthreads();
  int p = blockIdx.x * 256 + tid;
  float acc = db[0];
  #pragma unroll
  for (int i = 0; i < 64; i++) acc = fmaf(wsm[i], v[i * HWn + p], acc);
  out[p] = acc;
}

extern "C" void kernel_launch(void* const* d_in, const int* in_sizes, int n_in,
                              void* d_out, int out_size, void* d_ws, size_t ws_size,
                              hipStream_t stream) {
  const float* u     = (const float*)d_in[0];
  const float* x     = (const float*)d_in[1];
  const float* enc_w = (const float*)d_in[2];
  const float* enc_b = (const float*)d_in[3];
  const float* dec_w = (const float*)d_in[4];
  const float* dec_b = (const float*)d_in[5];
  const float* c1w   = (const float*)d_in[6];
  const float* c1b   = (const float*)d_in[7];
  const float* c2w   = (const float*)d_in[8];
  const float* c2b   = (const float*)d_in[9];
  const float* Are   = (const float*)d_in[10];
  const float* Aim   = (const float*)d_in[11];
  float* out = (float*)d_out;
  float* ws = (float*)d_ws;

  // workspace carve-up (floats):
  float* tw = ws;                                  // 1024
  float* v  = ws + 1024;                           // C*HW = 16,777,216
  float* s  = v + (size_t)Cn * HWn;                // C*HW
  float2* t1   = (float2*)(s + (size_t)Cn * HWn);  // C*H*M float2 (also 'e')
  float2* cbuf = t1 + (size_t)Cn * Hn * Mn;        // C*M*M float2
  float2* cmix = cbuf + (size_t)Cn * Mn * Mn;      // C*M*M float2
  // total = 155,193,344 bytes

  k_init_tw<<<dim3(1), dim3(512), 0, stream>>>(tw);
  k_encode<<<dim3(HWn / 256), dim3(256), 0, stream>>>(u, x, enc_w, enc_b, v);

  for (int l = 0; l < Ln; l++) {
    k_fwd1<<<dim3(Cn * Hn / 4), dim3(256), 0, stream>>>(v, tw, t1);
    hipMemsetAsync(cbuf, 0, (size_t)Cn * Mn * Mn * sizeof(float2), stream);
    k_fwd2<<<dim3(Cn, 8), dim3(256), 0, stream>>>(t1, tw, cbuf);
    k_mix<<<dim3(Mn, 16), dim3(256), 0, stream>>>(
        Are + (size_t)l * Cn * Cn * Mn * Mn, Aim + (size_t)l * Cn * Cn * Mn * Mn,
        cbuf, cmix);
    k_inv1<<<dim3(Cn, 8), dim3(256), 0, stream>>>(cmix, tw, t1);
    k_inv2<<<dim3(Cn * Hn / 4), dim3(256), 0, stream>>>((const float2*)t1, tw, s);
    k_conv<<<dim3(HWn / 256), dim3(256), 0, stream>>>(
        s, v, c1w + (size_t)l * 4096, c1b + (size_t)l * 64,
        c2w + (size_t)l * 4096, c2b + (size_t)l * 64);
  }

  k_decode<<<dim3(HWn / 256), dim3(256), 0, stream>>>(v, dec_w, dec_b, out);

  (void)in_sizes; (void)n_in; (void)out_size; (void)ws_size;
}

// Round 2
// 1791.753 us; speedup vs baseline: 1.9838x; 1.9838x over previous
//
#include <hip/hip_runtime.h>

// FNO forward, fp32. Round 2: conflict-free DFT kernels (fwd1/inv2) via
// phasor recurrence + radix-8 factorization; twiddle TABLE reads eliminated
// (they were lane-strided LDS reads -> massive bank conflicts, 1.23e8 cyc).
// Layout conventions:
//  v, s: [C][H][W] float
//  t1/e: [C][H][M] float2 (re, im)   (t1 and e share a buffer)
//  c, c2: [C][M][M] float2
//  tw: cos table [512], sin table [512]

constexpr int Hn = 512, Wn = 512, Cn = 64, Mn = 64, Ln = 4;
constexpr int HWn = Hn * Wn;

__device__ __forceinline__ float gelu_f(float x) {
  // jax.nn.gelu approximate=True: 0.5x(1+tanh(sqrt(2/pi)(x+0.044715x^3)))
  float t = 0.7978845608028654f * (x + 0.044715f * x * x * x);
  float e = __expf(2.0f * t);
  float th = 1.0f - 2.0f / (e + 1.0f);   // tanh(t), safe at +-inf
  return 0.5f * x * (1.0f + th);
}

__global__ __launch_bounds__(512) void k_init_tw(float* __restrict__ tw) {
  int j = threadIdx.x;  // 512 threads
  float ang = 6.283185307179586f * (float)j / 512.0f;
  tw[j] = cosf(ang);
  tw[512 + j] = sinf(ang);
}

__global__ __launch_bounds__(256) void k_encode(const float* __restrict__ u,
                                                const float* __restrict__ x,
                                                const float* __restrict__ ew,
                                                const float* __restrict__ eb,
                                                float* __restrict__ v) {
  __shared__ float w[Cn][3];
  __shared__ float b[Cn];
  int tid = threadIdx.x;
  if (tid < Cn) {
    w[tid][0] = ew[tid * 3 + 0];
    w[tid][1] = ew[tid * 3 + 1];
    w[tid][2] = ew[tid * 3 + 2];
    b[tid] = eb[tid];
  }
  __syncthreads();
  int p = blockIdx.x * 256 + tid;
  float x0 = x[p], x1 = x[HWn + p], uu = u[p];
  #pragma unroll 8
  for (int c = 0; c < Cn; c++)
    v[c * HWn + p] = fmaf(w[c][0], x0, fmaf(w[c][1], x1, fmaf(w[c][2], uu, b[c])));
}

// t1[ch,h,n] = sum_w v[ch,h,w] * exp(-2*pi*i*n*w/512)
// grid: C*H/4 blocks, 256 thr = 4 rows x 64 lanes(n).
// w = 8b+q factorization: twiddle(8b+q) = B_b * T_q; B rotated once per b.
// ac = sum_q [Tqc*Sc_q - Tqs*Ss_q], as = sum_q [Tqc*Ss_q + Tqs*Sc_q],
//   Sc_q = sum_b v[8b+q]*Bc_b, Ss_q = sum_b v[8b+q]*Bs_b.
__global__ __launch_bounds__(256) void k_fwd1(const float* __restrict__ v,
                                              const float* __restrict__ tw,
                                              float2* __restrict__ t1) {
  __shared__ float rows[4][512];
  int tid = threadIdx.x;
  int r = tid >> 6, n = tid & 63;
  int row = blockIdx.x * 4 + r;   // row = ch*512 + h
  const float* vr = v + (size_t)row * Wn;
  #pragma unroll
  for (int w8 = 0; w8 < 8; w8++) rows[r][n + 64 * w8] = vr[n + 64 * w8];

  // per-lane twiddle constants from the table (positive-angle cos/sin)
  float T1c = tw[n], T1s = tw[512 + n];                       // angle n*phi
  float R8c = tw[(8 * n) & 511], R8s = tw[512 + ((8 * n) & 511)];  // angle 8n*phi
  float Tqc[8], Tqs[8];
  Tqc[0] = 1.0f; Tqs[0] = 0.0f;
  #pragma unroll
  for (int q = 1; q < 8; q++) {
    float c_ = Tqc[q - 1] * T1c - Tqs[q - 1] * T1s;
    float s_ = Tqs[q - 1] * T1c + Tqc[q - 1] * T1s;
    Tqc[q] = c_; Tqs[q] = s_;
  }
  __syncthreads();

  float Sc[8], Ss[8];
  #pragma unroll
  for (int q = 0; q < 8; q++) { Sc[q] = 0.f; Ss[q] = 0.f; }
  float Bc = 1.0f, Bs = 0.0f;
  #pragma unroll 4
  for (int b = 0; b < 64; b++) {
    const float4* rp4 = (const float4*)&rows[r][8 * b];  // wave-uniform broadcast
    float4 v0 = rp4[0], v1 = rp4[1];
    Sc[0] = fmaf(v0.x, Bc, Sc[0]); Ss[0] = fmaf(v0.x, Bs, Ss[0]);
    Sc[1] = fmaf(v0.y, Bc, Sc[1]); Ss[1] = fmaf(v0.y, Bs, Ss[1]);
    Sc[2] = fmaf(v0.z, Bc, Sc[2]); Ss[2] = fmaf(v0.z, Bs, Ss[2]);
    Sc[3] = fmaf(v0.w, Bc, Sc[3]); Ss[3] = fmaf(v0.w, Bs, Ss[3]);
    Sc[4] = fmaf(v1.x, Bc, Sc[4]); Ss[4] = fmaf(v1.x, Bs, Ss[4]);
    Sc[5] = fmaf(v1.y, Bc, Sc[5]); Ss[5] = fmaf(v1.y, Bs, Ss[5]);
    Sc[6] = fmaf(v1.z, Bc, Sc[6]); Ss[6] = fmaf(v1.z, Bs, Ss[6]);
    Sc[7] = fmaf(v1.w, Bc, Sc[7]); Ss[7] = fmaf(v1.w, Bs, Ss[7]);
    float nBc = Bc * R8c - Bs * R8s;
    float nBs = Bs * R8c + Bc * R8s;
    Bc = nBc; Bs = nBs;
  }
  float ac = 0.f, as = 0.f;
  #pragma unroll
  for (int q = 0; q < 8; q++) {
    ac += Tqc[q] * Sc[q] - Tqs[q] * Ss[q];
    as += Tqc[q] * Ss[q] + Tqs[q] * Sc[q];
  }
  t1[row * 64 + n] = make_float2(ac, -as);
}

// c[ch,m,n] += (1/HW) sum_h t1[ch,h,n] * exp(-2*pi*i*(m-32)*h/512)
// grid: (C, 8 h-chunks), 256 thr = 4 m-groups x 64 lanes(n); atomic accumulate
__global__ __launch_bounds__(256) void k_fwd2(const float2* __restrict__ t1,
                                              const float* __restrict__ tw,
                                              float2* __restrict__ cb) {
  __shared__ float twc[512], tws[512];
  __shared__ float2 tsh[8][64];
  int tid = threadIdx.x;
  for (int j = tid; j < 512; j += 256) { twc[j] = tw[j]; tws[j] = tw[512 + j]; }
  int ch = blockIdx.x, hc = blockIdx.y;
  int n = tid & 63, mg = tid >> 6;
  float accr[16], acci[16];
  #pragma unroll
  for (int k = 0; k < 16; k++) { accr[k] = 0.f; acci[k] = 0.f; }
  for (int h8 = 0; h8 < 8; h8++) {
    __syncthreads();
    for (int j = tid; j < 512; j += 256) {
      int rr = j >> 6, nn = j & 63;
      tsh[rr][nn] = t1[(ch * 512 + hc * 64 + h8 * 8 + rr) * 64 + nn];
    }
    __syncthreads();
    #pragma unroll
    for (int rr = 0; rr < 8; rr++) {
      int h = hc * 64 + h8 * 8 + rr;
      float2 t = tsh[rr][n];
      #pragma unroll
      for (int k = 0; k < 16; k++) {
        int m = mg * 16 + k;
        int idx = ((m - 32) * h) & 511;     // wave-uniform -> broadcast
        float cc = twc[idx], ss = tws[idx];
        accr[k] = fmaf(t.x, cc, fmaf(t.y, ss, accr[k]));
        acci[k] = fmaf(t.y, cc, fmaf(-t.x, ss, acci[k]));
      }
    }
  }
  const float sc = 1.0f / 262144.0f;  // 1/(H*W), norm='forward'
  #pragma unroll
  for (int k = 0; k < 16; k++) {
    int m = mg * 16 + k;
    atomicAdd(&cb[(ch * 64 + m) * 64 + n].x, accr[k] * sc);
    atomicAdd(&cb[(ch * 64 + m) * 64 + n].y, acci[k] * sc);
  }
}

// c2[o,m,n] = sum_i A[o,i,m,n] * c[i,m,n]  (complex). Memory-bound on A.
__global__ __launch_bounds__(256) void k_mix(const float* __restrict__ Ar,
                                             const float* __restrict__ Ai,
                                             const float2* __restrict__ cb,
                                             float2* __restrict__ c2b) {
  __shared__ float2 csh[64][64];   // c[i][n] at fixed m
  int tid = threadIdx.x;
  int m = blockIdx.x, og = blockIdx.y;
  for (int j = tid; j < 4096; j += 256) {
    int i = j >> 6, n = j & 63;
    csh[i][n] = cb[(i * 64 + m) * 64 + n];
  }
  __syncthreads();
  int o = og * 4 + (tid >> 6);
  int n = tid & 63;
  const float* ar = Ar + (size_t)o * 64 * 4096 + m * 64 + n;
  const float* ai = Ai + (size_t)o * 64 * 4096 + m * 64 + n;
  float accr = 0.f, acci = 0.f;
  #pragma unroll 8
  for (int i = 0; i < 64; i++) {
    float a_r = ar[i * 4096];
    float a_i = ai[i * 4096];
    float2 cv = csh[i][n];
    accr = fmaf(a_r, cv.x, fmaf(-a_i, cv.y, accr));
    acci = fmaf(a_r, cv.y, fmaf(a_i, cv.x, acci));
  }
  c2b[(o * 64 + m) * 64 + n] = make_float2(accr, acci);
}

// e[ch,h,n] = sum_m c2[ch,m,n] * exp(+2*pi*i*(m-32)*h/512)
__global__ __launch_bounds__(256) void k_inv1(const float2* __restrict__ c2buf,
                                              const float* __restrict__ tw,
                                              float2* __restrict__ e) {
  __shared__ float twc[512], tws[512];
  __shared__ float2 csh[64][64];
  int tid = threadIdx.x;
  for (int j = tid; j < 512; j += 256) { twc[j] = tw[j]; tws[j] = tw[512 + j]; }
  int ch = blockIdx.x, hc = blockIdx.y;
  for (int j = tid; j < 4096; j += 256) csh[j >> 6][j & 63] = c2buf[ch * 4096 + j];
  __syncthreads();
  int n = tid & 63, hs = tid >> 6;
  for (int k = 0; k < 16; k++) {
    int h = hc * 64 + hs * 16 + k;
    float er = 0.f, ei = 0.f;
    #pragma unroll 8
    for (int mm = 0; mm < 64; mm++) {
      int idx = ((mm - 32) * h) & 511;      // wave-uniform -> broadcast
      float cc = twc[idx], ss = tws[idx];
      float2 t = csh[mm][n];
      er = fmaf(t.x, cc, fmaf(-t.y, ss, er));
      ei = fmaf(t.y, cc, fmaf(t.x, ss, ei));
    }
    e[(ch * 512 + h) * 64 + n] = make_float2(er, ei);
  }
}

// s[ch,h,w] = Re( sum_n E[n] * exp(+2*pi*i*n*w/512) ),  E pre-doubled.
// grid: C*H/4 blocks, 256 thr = 4 rows x 64 lanes(w0); lane does w = w0+64j.
// Factor: angle = n*w0*phi + 2*pi*(n*j mod 8)/8. Maintain phasor B (angle
// n*w0*phi, rotate by w0*phi per n). 8th-root coefficients are compile-time
// constants once n = 8a+r is unrolled over r (k = (r*j)&7).
__global__ __launch_bounds__(256) void k_inv2(const float2* __restrict__ e,
                                              const float* __restrict__ tw,
                                              float* __restrict__ s) {
  __shared__ float er[4][64], ei[4][64];
  int tid = threadIdx.x;
  int r = tid >> 6, lane = tid & 63;
  int row = blockIdx.x * 4 + r;   // ch*512 + h
  float2 t = e[row * 64 + lane];
  float alpha = (lane == 0) ? 1.0f : 2.0f;  // Hermitian doubling; Im(bin0) dropped
  er[r][lane] = t.x * alpha;
  ei[r][lane] = t.y * alpha;
  float Rc = tw[lane], Rs = tw[512 + lane];   // rotate-by-(w0*phi) per n-step
  __syncthreads();
  float acc[8];
  #pragma unroll
  for (int j = 0; j < 8; j++) acc[j] = 0.f;
  float Bc = 1.0f, Bs = 0.0f;
  const float C45 = 0.70710678118654752f;
  for (int a = 0; a < 8; a++) {
    #pragma unroll
    for (int rr = 0; rr < 8; rr++) {
      int n = 8 * a + rr;
      float R = er[r][n], I = ei[r][n];     // wave-uniform broadcast
      float Tre = R * Bc - I * Bs;
      float Tim = R * Bs + I * Bc;
      float P = C45 * (Tre - Tim);
      float Q = C45 * (Tre + Tim);
      #pragma unroll
      for (int j = 0; j < 8; j++) {
        int k = (rr * j) & 7;               // compile-time after unroll
        float add = (k == 0) ? Tre
                  : (k == 1) ? P
                  : (k == 2) ? -Tim
                  : (k == 3) ? -Q
                  : (k == 4) ? -Tre
                  : (k == 5) ? -P
                  : (k == 6) ? Tim
                  : Q;
        acc[j] += add;
      }
      float nBc = Bc * Rc - Bs * Rs;
      float nBs = Bs * Rc + Bc * Rs;
      Bc = nBc; Bs = nBs;
    }
  }
  #pragma unroll
  for (int j = 0; j < 8; j++) s[(size_t)row * 512 + lane + 64 * j] = acc[j];
}

// v[:,p] += gelu(W2 @ gelu(W1 @ s[:,p] + b1) + b2), fused per pixel
__global__ __launch_bounds__(256) void k_conv(const float* __restrict__ s,
                                              float* __restrict__ v,
                                              const float* __restrict__ w1,
                                              const float* __restrict__ b1,
                                              const float* __restrict__ w2,
                                              const float* __restrict__ b2) {
  __shared__ float4 W1[64][16];    // W1[o][i/4]
  __shared__ float W2T[64][64];    // W2T[i][o] = w2[o,i]
  __shared__ float B1[64], B2[64];
  int tid = threadIdx.x;
  float* W1f = (float*)W1;
  for (int j = tid; j < 4096; j += 256) {
    W1f[j] = w1[j];
    W2T[j & 63][j >> 6] = w2[j];
  }
  if (tid < 64) { B1[tid] = b1[tid]; B2[tid] = b2[tid]; }
  __syncthreads();
  int p = blockIdx.x * 256 + tid;
  float sv[64];
  #pragma unroll
  for (int i = 0; i < 64; i++) sv[i] = s[i * HWn + p];
  float acc2[64];
  #pragma unroll
  for (int o = 0; o < 64; o++) acc2[o] = B2[o];
  for (int i = 0; i < 64; i++) {
    float a = B1[i];
    #pragma unroll
    for (int k4 = 0; k4 < 16; k4++) {
      float4 ww = W1[i][k4];
      a = fmaf(ww.x, sv[4 * k4 + 0], a);
      a = fmaf(ww.y, sv[4 * k4 + 1], a);
      a = fmaf(ww.z, sv[4 * k4 + 2], a);
      a = fmaf(ww.w, sv[4 * k4 + 3], a);
    }
    float g = gelu_f(a);
    const float4* w2r = (const float4*)W2T[i];
    #pragma unroll
    for (int o4 = 0; o4 < 16; o4++) {
      float4 ww = w2r[o4];
      acc2[4 * o4 + 0] = fmaf(ww.x, g, acc2[4 * o4 + 0]);
      acc2[4 * o4 + 1] = fmaf(ww.y, g, acc2[4 * o4 + 1]);
      acc2[4 * o4 + 2] = fmaf(ww.z, g, acc2[4 * o4 + 2]);
      acc2[4 * o4 + 3] = fmaf(ww.w, g, acc2[4 * o4 + 3]);
    }
  }
  #pragma unroll
  for (int o = 0; o < 64; o++) v[o * HWn + p] += gelu_f(acc2[o]);
}

__global__ __launch_bounds__(256) void k_decode(const float* __restrict__ v,
                                                const float* __restrict__ dw,
                                                const float* __restrict__ db,
                                                float* __restrict__ out) {
  __shared__ float wsm[64];
  int tid = threadIdx.x;
  if (tid < 64) wsm[tid] = dw[tid];
  __syncthreads();
  int p = blockIdx.x * 256 + tid;
  float acc = db[0];
  #pragma unroll
  for (int i = 0; i < 64; i++) acc = fmaf(wsm[i], v[i * HWn + p], acc);
  out[p] = acc;
}

extern "C" void kernel_launch(void* const* d_in, const int* in_sizes, int n_in,
                              void* d_out, int out_size, void* d_ws, size_t ws_size,
                              hipStream_t stream) {
  const float* u     = (const float*)d_in[0];
  const float* x     = (const float*)d_in[1];
  const float* enc_w = (const float*)d_in[2];
  const float* enc_b = (const float*)d_in[3];
  const float* dec_w = (const float*)d_in[4];
  const float* dec_b = (const float*)d_in[5];
  const float* c1w   = (const float*)d_in[6];
  const float* c1b   = (const float*)d_in[7];
  const float* c2w   = (const float*)d_in[8];
  const float* c2b   = (const float*)d_in[9];
  const float* Are   = (const float*)d_in[10];
  const float* Aim   = (const float*)d_in[11];
  float* out = (float*)d_out;
  float* ws = (float*)d_ws;

  // workspace carve-up (floats):
  float* tw = ws;                                  // 1024
  float* v  = ws + 1024;                           // C*HW
  float* s  = v + (size_t)Cn * HWn;                // C*HW
  float2* t1   = (float2*)(s + (size_t)Cn * HWn);  // C*H*M float2 (also 'e')
  float2* cbuf = t1 + (size_t)Cn * Hn * Mn;        // C*M*M float2
  float2* cmix = cbuf + (size_t)Cn * Mn * Mn;      // C*M*M float2

  k_init_tw<<<dim3(1), dim3(512), 0, stream>>>(tw);
  k_encode<<<dim3(HWn / 256), dim3(256), 0, stream>>>(u, x, enc_w, enc_b, v);

  for (int l = 0; l < Ln; l++) {
    k_fwd1<<<dim3(Cn * Hn / 4), dim3(256), 0, stream>>>(v, tw, t1);
    hipMemsetAsync(cbuf, 0, (size_t)Cn * Mn * Mn * sizeof(float2), stream);
    k_fwd2<<<dim3(Cn, 8), dim3(256), 0, stream>>>(t1, tw, cbuf);
    k_mix<<<dim3(Mn, 16), dim3(256), 0, stream>>>(
        Are + (size_t)l * Cn * Cn * Mn * Mn, Aim + (size_t)l * Cn * Cn * Mn * Mn,
        cbuf, cmix);
    k_inv1<<<dim3(Cn, 8), dim3(256), 0, stream>>>(cmix, tw, t1);
    k_inv2<<<dim3(Cn * Hn / 4), dim3(256), 0, stream>>>((const float2*)t1, tw, s);
    k_conv<<<dim3(HWn / 256), dim3(256), 0, stream>>>(
        s, v, c1w + (size_t)l * 4096, c1b + (size_t)l * 64,
        c2w + (size_t)l * 4096, c2b + (size_t)l * 64);
  }

  k_decode<<<dim3(HWn / 256), dim3(256), 0, stream>>>(v, dec_w, dec_b, out);

  (void)in_sizes; (void)n_in; (void)out_size; (void)ws_size;
}

// Round 3
// 1582.938 us; speedup vs baseline: 2.2455x; 1.1319x over previous
//
#include <hip/hip_runtime.h>

// FNO forward. Round 3:
//  - k_conv rewritten as f16 MFMA (16x16x32, fp32 accum): GEMM1 -> gelu ->
//    LDS repack -> GEMM2 -> gelu -> coalesced v+=. Old version was a 64-deep
//    serial fp32 fma chain (latency-bound).
//  - k_fwd2: single LDS stage (1 barrier instead of 16), padded rows.
//  - k_fwd2/k_inv1/k_mix: LDS float2 arrays padded to 65 (4-way -> 2-way).
// Layouts: v,s: [C][H][W] f32; t1/e: [C][H][M] float2; c,c2: [C][M][M] float2.

constexpr int Hn = 512, Wn = 512, Cn = 64, Mn = 64, Ln = 4;
constexpr int HWn = Hn * Wn;

typedef _Float16 half8 __attribute__((ext_vector_type(8)));
typedef float f32x4 __attribute__((ext_vector_type(4)));

__device__ __forceinline__ float gelu_f(float x) {
  // jax.nn.gelu approximate=True
  float t = 0.7978845608028654f * (x + 0.044715f * x * x * x);
  float e = __expf(2.0f * t);
  float th = 1.0f - 2.0f / (e + 1.0f);
  return 0.5f * x * (1.0f + th);
}

__global__ __launch_bounds__(512) void k_init_tw(float* __restrict__ tw) {
  int j = threadIdx.x;
  float ang = 6.283185307179586f * (float)j / 512.0f;
  tw[j] = cosf(ang);
  tw[512 + j] = sinf(ang);
}

__global__ __launch_bounds__(256) void k_encode(const float* __restrict__ u,
                                                const float* __restrict__ x,
                                                const float* __restrict__ ew,
                                                const float* __restrict__ eb,
                                                float* __restrict__ v) {
  __shared__ float w[Cn][3];
  __shared__ float b[Cn];
  int tid = threadIdx.x;
  if (tid < Cn) {
    w[tid][0] = ew[tid * 3 + 0];
    w[tid][1] = ew[tid * 3 + 1];
    w[tid][2] = ew[tid * 3 + 2];
    b[tid] = eb[tid];
  }
  __syncthreads();
  int p = blockIdx.x * 256 + tid;
  float x0 = x[p], x1 = x[HWn + p], uu = u[p];
  #pragma unroll 8
  for (int c = 0; c < Cn; c++)
    v[c * HWn + p] = fmaf(w[c][0], x0, fmaf(w[c][1], x1, fmaf(w[c][2], uu, b[c])));
}

// t1[row,n] = sum_w v[row,w] * exp(-2*pi*i*n*w/512); radix-8 phasor recurrence.
__global__ __launch_bounds__(256) void k_fwd1(const float* __restrict__ v,
                                              const float* __restrict__ tw,
                                              float2* __restrict__ t1) {
  __shared__ float rows[4][512];
  int tid = threadIdx.x;
  int r = tid >> 6, n = tid & 63;
  int row = blockIdx.x * 4 + r;
  const float* vr = v + (size_t)row * Wn;
  #pragma unroll
  for (int w8 = 0; w8 < 8; w8++) rows[r][n + 64 * w8] = vr[n + 64 * w8];

  float T1c = tw[n], T1s = tw[512 + n];
  float R8c = tw[(8 * n) & 511], R8s = tw[512 + ((8 * n) & 511)];
  float Tqc[8], Tqs[8];
  Tqc[0] = 1.0f; Tqs[0] = 0.0f;
  #pragma unroll
  for (int q = 1; q < 8; q++) {
    float c_ = Tqc[q - 1] * T1c - Tqs[q - 1] * T1s;
    float s_ = Tqs[q - 1] * T1c + Tqc[q - 1] * T1s;
    Tqc[q] = c_; Tqs[q] = s_;
  }
  __syncthreads();

  float Sc[8], Ss[8];
  #pragma unroll
  for (int q = 0; q < 8; q++) { Sc[q] = 0.f; Ss[q] = 0.f; }
  float Bc = 1.0f, Bs = 0.0f;
  #pragma unroll 4
  for (int b = 0; b < 64; b++) {
    const float4* rp4 = (const float4*)&rows[r][8 * b];
    float4 v0 = rp4[0], v1 = rp4[1];
    Sc[0] = fmaf(v0.x, Bc, Sc[0]); Ss[0] = fmaf(v0.x, Bs, Ss[0]);
    Sc[1] = fmaf(v0.y, Bc, Sc[1]); Ss[1] = fmaf(v0.y, Bs, Ss[1]);
    Sc[2] = fmaf(v0.z, Bc, Sc[2]); Ss[2] = fmaf(v0.z, Bs, Ss[2]);
    Sc[3] = fmaf(v0.w, Bc, Sc[3]); Ss[3] = fmaf(v0.w, Bs, Ss[3]);
    Sc[4] = fmaf(v1.x, Bc, Sc[4]); Ss[4] = fmaf(v1.x, Bs, Ss[4]);
    Sc[5] = fmaf(v1.y, Bc, Sc[5]); Ss[5] = fmaf(v1.y, Bs, Ss[5]);
    Sc[6] = fmaf(v1.z, Bc, Sc[6]); Ss[6] = fmaf(v1.z, Bs, Ss[6]);
    Sc[7] = fmaf(v1.w, Bc, Sc[7]); Ss[7] = fmaf(v1.w, Bs, Ss[7]);
    float nBc = Bc * R8c - Bs * R8s;
    float nBs = Bs * R8c + Bc * R8s;
    Bc = nBc; Bs = nBs;
  }
  float ac = 0.f, as = 0.f;
  #pragma unroll
  for (int q = 0; q < 8; q++) {
    ac += Tqc[q] * Sc[q] - Tqs[q] * Ss[q];
    as += Tqc[q] * Ss[q] + Tqs[q] * Sc[q];
  }
  t1[row * 64 + n] = make_float2(ac, -as);
}

// c[ch,m,n] += (1/HW) sum_h t1[ch,h,n] * exp(-2*pi*i*(m-32)*h/512)
__global__ __launch_bounds__(256) void k_fwd2(const float2* __restrict__ t1,
                                              const float* __restrict__ tw,
                                              float2* __restrict__ cb) {
  __shared__ float twc[512], tws[512];
  __shared__ float2 tsh[64][65];      // +1 pad: 2-way banks
  int tid = threadIdx.x;
  for (int j = tid; j < 512; j += 256) { twc[j] = tw[j]; tws[j] = tw[512 + j]; }
  int ch = blockIdx.x, hc = blockIdx.y;
  int n = tid & 63, mg = tid >> 6;
  for (int j = tid; j < 4096; j += 256)
    tsh[j >> 6][j & 63] = t1[(ch * 512 + hc * 64 + (j >> 6)) * 64 + (j & 63)];
  __syncthreads();
  float accr[16], acci[16];
  #pragma unroll
  for (int k = 0; k < 16; k++) { accr[k] = 0.f; acci[k] = 0.f; }
  for (int rr = 0; rr < 64; rr++) {
    int h = hc * 64 + rr;
    float2 t = tsh[rr][n];
    #pragma unroll
    for (int k = 0; k < 16; k++) {
      int m = mg * 16 + k;
      int idx = ((m - 32) * h) & 511;   // wave-uniform -> broadcast
      float cc = twc[idx], ss = tws[idx];
      accr[k] = fmaf(t.x, cc, fmaf(t.y, ss, accr[k]));
      acci[k] = fmaf(t.y, cc, fmaf(-t.x, ss, acci[k]));
    }
  }
  const float sc = 1.0f / 262144.0f;
  #pragma unroll
  for (int k = 0; k < 16; k++) {
    int m = mg * 16 + k;
    atomicAdd(&cb[(ch * 64 + m) * 64 + n].x, accr[k] * sc);
    atomicAdd(&cb[(ch * 64 + m) * 64 + n].y, acci[k] * sc);
  }
}

// c2[o,m,n] = sum_i A[o,i,m,n] * c[i,m,n]  (complex). Memory-bound on A.
__global__ __launch_bounds__(256) void k_mix(const float* __restrict__ Ar,
                                             const float* __restrict__ Ai,
                                             const float2* __restrict__ cb,
                                             float2* __restrict__ c2b) {
  __shared__ float2 csh[64][65];
  int tid = threadIdx.x;
  int m = blockIdx.x, og = blockIdx.y;
  for (int j = tid; j < 4096; j += 256) {
    int i = j >> 6, n = j & 63;
    csh[i][n] = cb[(i * 64 + m) * 64 + n];
  }
  __syncthreads();
  int o = og * 4 + (tid >> 6);
  int n = tid & 63;
  const float* ar = Ar + (size_t)o * 64 * 4096 + m * 64 + n;
  const float* ai = Ai + (size_t)o * 64 * 4096 + m * 64 + n;
  float accr = 0.f, acci = 0.f;
  #pragma unroll 8
  for (int i = 0; i < 64; i++) {
    float a_r = ar[i * 4096];
    float a_i = ai[i * 4096];
    float2 cv = csh[i][n];
    accr = fmaf(a_r, cv.x, fmaf(-a_i, cv.y, accr));
    acci = fmaf(a_r, cv.y, fmaf(a_i, cv.x, acci));
  }
  c2b[(o * 64 + m) * 64 + n] = make_float2(accr, acci);
}

// e[ch,h,n] = sum_m c2[ch,m,n] * exp(+2*pi*i*(m-32)*h/512)
__global__ __launch_bounds__(256) void k_inv1(const float2* __restrict__ c2buf,
                                              const float* __restrict__ tw,
                                              float2* __restrict__ e) {
  __shared__ float twc[512], tws[512];
  __shared__ float2 csh[64][65];
  int tid = threadIdx.x;
  for (int j = tid; j < 512; j += 256) { twc[j] = tw[j]; tws[j] = tw[512 + j]; }
  int ch = blockIdx.x, hc = blockIdx.y;
  for (int j = tid; j < 4096; j += 256) csh[j >> 6][j & 63] = c2buf[ch * 4096 + j];
  __syncthreads();
  int n = tid & 63, hs = tid >> 6;
  for (int k = 0; k < 16; k++) {
    int h = hc * 64 + hs * 16 + k;
    float er = 0.f, ei = 0.f;
    #pragma unroll 8
    for (int mm = 0; mm < 64; mm++) {
      int idx = ((mm - 32) * h) & 511;
      float cc = twc[idx], ss = tws[idx];
      float2 t = csh[mm][n];
      er = fmaf(t.x, cc, fmaf(-t.y, ss, er));
      ei = fmaf(t.y, cc, fmaf(t.x, ss, ei));
    }
    e[(ch * 512 + h) * 64 + n] = make_float2(er, ei);
  }
}

// s[row,w] = Re( sum_n E[n] * exp(+2*pi*i*n*w/512) ), radix-8 phasor.
__global__ __launch_bounds__(256) void k_inv2(const float2* __restrict__ e,
                                              const float* __restrict__ tw,
                                              float* __restrict__ s) {
  __shared__ float er[4][64], ei[4][64];
  int tid = threadIdx.x;
  int r = tid >> 6, lane = tid & 63;
  int row = blockIdx.x * 4 + r;
  float2 t = e[row * 64 + lane];
  float alpha = (lane == 0) ? 1.0f : 2.0f;
  er[r][lane] = t.x * alpha;
  ei[r][lane] = t.y * alpha;
  float Rc = tw[lane], Rs = tw[512 + lane];
  __syncthreads();
  float acc[8];
  #pragma unroll
  for (int j = 0; j < 8; j++) acc[j] = 0.f;
  float Bc = 1.0f, Bs = 0.0f;
  const float C45 = 0.70710678118654752f;
  for (int a = 0; a < 8; a++) {
    #pragma unroll
    for (int rr = 0; rr < 8; rr++) {
      float R = er[r][8 * a + rr], I = ei[r][8 * a + rr];
      float Tre = R * Bc - I * Bs;
      float Tim = R * Bs + I * Bc;
      float P = C45 * (Tre - Tim);
      float Q = C45 * (Tre + Tim);
      #pragma unroll
      for (int j = 0; j < 8; j++) {
        int k = (rr * j) & 7;
        float add = (k == 0) ? Tre
                  : (k == 1) ? P
                  : (k == 2) ? -Tim
                  : (k == 3) ? -Q
                  : (k == 4) ? -Tre
                  : (k == 5) ? -P
                  : (k == 6) ? Tim
                  : Q;
        acc[j] += add;
      }
      float nBc = Bc * Rc - Bs * Rs;
      float nBs = Bs * Rc + Bc * Rs;
      Bc = nBc; Bs = nBs;
    }
  }
  #pragma unroll
  for (int j = 0; j < 8; j++) s[(size_t)row * 512 + lane + 64 * j] = acc[j];
}

// v[:,p] += gelu(W2 @ gelu(W1 @ s[:,p] + b1) + b2)  -- f16 MFMA version.
// Block = 64-pixel tile, 4 waves; wave w owns pixel sub-tile [16w,16w+16).
// LDS rows padded to 72 f16 (16B-aligned, 2-way banks only).
__global__ __launch_bounds__(256) void k_conv(const float* __restrict__ s,
                                              float* __restrict__ v,
                                              const float* __restrict__ w1,
                                              const float* __restrict__ b1,
                                              const float* __restrict__ w2,
                                              const float* __restrict__ b2) {
  __shared__ _Float16 W1h[64 * 72];   // [o][i]
  __shared__ _Float16 W2h[64 * 72];   // [o][i]
  __shared__ _Float16 XpY2[64 * 72];  // Xp[p][i]; reused as Y2h[o][p] stride 66
  __shared__ _Float16 Y1T[64 * 72];   // [p][o]
  __shared__ float B1[64], B2[64];
  int tid = threadIdx.x;
  int pb = blockIdx.x * 64;

  for (int j = tid; j < 4096; j += 256) {
    int a_ = j >> 6, b_ = j & 63;
    W1h[a_ * 72 + b_] = (_Float16)w1[j];
    W2h[a_ * 72 + b_] = (_Float16)w2[j];
    XpY2[b_ * 72 + a_] = (_Float16)s[(size_t)a_ * HWn + pb + b_];  // Xp[p][i]
  }
  if (tid < 64) { B1[tid] = b1[tid]; B2[tid] = b2[tid]; }
  __syncthreads();

  int wv = tid >> 6, lane = tid & 63;
  int col = lane & 15, quad = lane >> 4;
  int prow = 16 * wv + col;           // this lane's pixel (B-operand n / D col)

  // ---- GEMM1: D1[o][p] = W1 * X ----
  f32x4 acc1[4];
  #pragma unroll
  for (int ot = 0; ot < 4; ot++) acc1[ot] = (f32x4){0.f, 0.f, 0.f, 0.f};
  half8 bfr[2];
  #pragma unroll
  for (int kh = 0; kh < 2; kh++)
    bfr[kh] = *(const half8*)&XpY2[prow * 72 + kh * 32 + quad * 8];
  #pragma unroll
  for (int ot = 0; ot < 4; ot++) {
    #pragma unroll
    for (int kh = 0; kh < 2; kh++) {
      half8 afr = *(const half8*)&W1h[(ot * 16 + col) * 72 + kh * 32 + quad * 8];
      acc1[ot] = __builtin_amdgcn_mfma_f32_16x16x32_f16(afr, bfr[kh], acc1[ot], 0, 0, 0);
    }
  }
  // epilogue 1: gelu(d + b1) -> Y1T[p][o] (f16), 8B packed writes
  #pragma unroll
  for (int ot = 0; ot < 4; ot++) {
    int o0 = ot * 16 + quad * 4;
    union { _Float16 h[4]; uint2 u; } pk;
    #pragma unroll
    for (int r = 0; r < 4; r++)
      pk.h[r] = (_Float16)gelu_f(acc1[ot][r] + B1[o0 + r]);
    *(uint2*)&Y1T[prow * 72 + o0] = pk.u;
  }
  __syncthreads();   // also guarantees all waves' Xp reads are done

  // ---- GEMM2: D2[o][p] = W2 * Y1 ----
  f32x4 acc2[4];
  #pragma unroll
  for (int ot = 0; ot < 4; ot++) acc2[ot] = (f32x4){0.f, 0.f, 0.f, 0.f};
  #pragma unroll
  for (int kh = 0; kh < 2; kh++)
    bfr[kh] = *(const half8*)&Y1T[prow * 72 + kh * 32 + quad * 8];
  #pragma unroll
  for (int ot = 0; ot < 4; ot++) {
    #pragma unroll
    for (int kh = 0; kh < 2; kh++) {
      half8 afr = *(const half8*)&W2h[(ot * 16 + col) * 72 + kh * 32 + quad * 8];
      acc2[ot] = __builtin_amdgcn_mfma_f32_16x16x32_f16(afr, bfr[kh], acc2[ot], 0, 0, 0);
    }
  }
  // epilogue 2: gelu(d + b2) -> Y2h[o][p] (stride 66, over Xp region)
  #pragma unroll
  for (int ot = 0; ot < 4; ot++) {
    int o0 = ot * 16 + quad * 4;
    #pragma unroll
    for (int r = 0; r < 4; r++)
      XpY2[(o0 + r) * 66 + prow] = (_Float16)gelu_f(acc2[ot][r] + B2[o0 + r]);
  }
  __syncthreads();

  // drain: v[o][p] += Y2h[o][p], fully coalesced over p
  for (int j = tid; j < 4096; j += 256) {
    int o = j >> 6, p = j & 63;
    v[(size_t)o * HWn + pb + p] += (float)XpY2[o * 66 + p];
  }
}

__global__ __launch_bounds__(256) void k_decode(const float* __restrict__ v,
                                                const float* __restrict__ dw,
                                                const float* __restrict__ db,
                                                float* __restrict__ out) {
  __shared__ float wsm[64];
  int tid = threadIdx.x;
  if (tid < 64) wsm[tid] = dw[tid];
  __syncthreads();
  int p = blockIdx.x * 256 + tid;
  float acc = db[0];
  #pragma unroll
  for (int i = 0; i < 64; i++) acc = fmaf(wsm[i], v[i * HWn + p], acc);
  out[p] = acc;
}

extern "C" void kernel_launch(void* const* d_in, const int* in_sizes, int n_in,
                              void* d_out, int out_size, void* d_ws, size_t ws_size,
                              hipStream_t stream) {
  const float* u     = (const float*)d_in[0];
  const float* x     = (const float*)d_in[1];
  const float* enc_w = (const float*)d_in[2];
  const float* enc_b = (const float*)d_in[3];
  const float* dec_w = (const float*)d_in[4];
  const float* dec_b = (const float*)d_in[5];
  const float* c1w   = (const float*)d_in[6];
  const float* c1b   = (const float*)d_in[7];
  const float* c2w   = (const float*)d_in[8];
  const float* c2b   = (const float*)d_in[9];
  const float* Are   = (const float*)d_in[10];
  const float* Aim   = (const float*)d_in[11];
  float* out = (float*)d_out;
  float* ws = (float*)d_ws;

  float* tw = ws;
  float* v  = ws + 1024;
  float* s  = v + (size_t)Cn * HWn;
  float2* t1   = (float2*)(s + (size_t)Cn * HWn);
  float2* cbuf = t1 + (size_t)Cn * Hn * Mn;
  float2* cmix = cbuf + (size_t)Cn * Mn * Mn;

  k_init_tw<<<dim3(1), dim3(512), 0, stream>>>(tw);
  k_encode<<<dim3(HWn / 256), dim3(256), 0, stream>>>(u, x, enc_w, enc_b, v);

  for (int l = 0; l < Ln; l++) {
    k_fwd1<<<dim3(Cn * Hn / 4), dim3(256), 0, stream>>>(v, tw, t1);
    hipMemsetAsync(cbuf, 0, (size_t)Cn * Mn * Mn * sizeof(float2), stream);
    k_fwd2<<<dim3(Cn, 8), dim3(256), 0, stream>>>(t1, tw, cbuf);
    k_mix<<<dim3(Mn, 16), dim3(256), 0, stream>>>(
        Are + (size_t)l * Cn * Cn * Mn * Mn, Aim + (size_t)l * Cn * Cn * Mn * Mn,
        cbuf, cmix);
    k_inv1<<<dim3(Cn, 8), dim3(256), 0, stream>>>(cmix, tw, t1);
    k_inv2<<<dim3(Cn * Hn / 4), dim3(256), 0, stream>>>((const float2*)t1, tw, s);
    k_conv<<<dim3(HWn / 64), dim3(256), 0, stream>>>(
        s, v, c1w + (size_t)l * 4096, c1b + (size_t)l * 64,
        c2w + (size_t)l * 4096, c2b + (size_t)l * 64);
  }

  k_decode<<<dim3(HWn / 256), dim3(256), 0, stream>>>(v, dec_w, dec_b, out);

  (void)in_sizes; (void)n_in; (void)out_size; (void)ws_size;
}